// Round 1
// baseline (550.079 us; speedup 1.0000x reference)
//
#include <hip/hip_runtime.h>

// ---------------------------------------------------------------------------
// RVMixtureSynthesizers: q = query@Wq^T + bq ; k = key@Wk^T + bk
//   energy = q@k^T + attn_bias ; attention = softmax(energy) ; out = attention@value
// Outputs (concatenated in d_out): out [16,1024,1024] fp32, attention [16,1024,1024] fp32
//
// Precision: split-bf16 (hi+lo, 3 MFMA products) for proj and QK^T so energy is
// accurate to ~1e-3 (softmax is near-argmax: energy sigma~32, ties amplify error).
// PV uses plain bf16.
//
// Workspace need: 200 MiB exactly (6*BSD + 4*D*D bf16 elements).
// ---------------------------------------------------------------------------

#define AS1 __attribute__((address_space(1)))
#define AS3 __attribute__((address_space(3)))

typedef __bf16 bf16;
typedef __bf16 bf16x4 __attribute__((ext_vector_type(4)));
typedef __bf16 bf16x8 __attribute__((ext_vector_type(8)));
typedef float  f32x4  __attribute__((ext_vector_type(4)));

constexpr int BATCH = 16;
constexpr int S = 1024;
constexpr int D = 1024;
constexpr long NBSD = (long)BATCH * S * D;   // 16777216 elements

constexpr int BM = 128, BN = 128, BK = 32;

// ---------------------------------------------------------------------------
// fp32 -> (hi bf16, lo bf16) split conversion, vectorized x4
__global__ __launch_bounds__(256) void split_convert(
    const float* __restrict__ in, bf16* __restrict__ hi, bf16* __restrict__ lo, int n4) {
  int i = blockIdx.x * blockDim.x + threadIdx.x;
  int stride = gridDim.x * blockDim.x;
  for (; i < n4; i += stride) {
    f32x4 x = ((const f32x4*)in)[i];
    bf16x4 h, l;
#pragma unroll
    for (int j = 0; j < 4; ++j) {
      float v = x[j];
      bf16 hh = (bf16)v;
      h[j] = hh;
      l[j] = (bf16)(v - (float)hh);   // x - hi is exact in fp32
    }
    ((bf16x4*)hi)[i] = h;
    ((bf16x4*)lo)[i] = l;
  }
}

// ---------------------------------------------------------------------------
// value [b][t][d] fp32 -> valueT [b][d][t] bf16 (so PV GEMM gets B^T layout)
__global__ __launch_bounds__(256) void transpose_convert(
    const float* __restrict__ v, bf16* __restrict__ vT) {
  __shared__ float tile[32][33];
  const int b = blockIdx.z;
  const int t0 = blockIdx.y * 32, d0 = blockIdx.x * 32;
  const int tx = threadIdx.x & 31, ty = threadIdx.x >> 5;  // 32 x 8
  const float* src = v + (long)b * S * D;
#pragma unroll
  for (int i = 0; i < 4; ++i)
    tile[ty + i * 8][tx] = src[(long)(t0 + ty + i * 8) * D + d0 + tx];
  __syncthreads();
  bf16* dst = vT + (long)b * D * S;
#pragma unroll
  for (int i = 0; i < 4; ++i)
    dst[(long)(d0 + ty + i * 8) * S + t0 + tx] = (bf16)tile[tx][ty + i * 8];
}

// ---------------------------------------------------------------------------
// Split-bf16 GEMM: C[m,n] = sum_k (Ah+Al)[m,k] * (Bh+Bl)[n,k]  (B^T layout)
// EPI=0: proj — add bias[col], write split bf16 (Ch,Cl), ld=D
// EPI=1: energy — add bias[row*S+col] (attn_bias), write fp32 Cf (per-batch)
template <int EPI>
__global__ __launch_bounds__(256, 2) void gemm_split(
    const bf16* __restrict__ Ah_g, const bf16* __restrict__ Al_g, long a_bstride,
    const bf16* __restrict__ Bh_g, const bf16* __restrict__ Bl_g, long b_bstride,
    const float* __restrict__ bias,
    bf16* __restrict__ Ch, bf16* __restrict__ Cl,
    float* __restrict__ Cf, long c_bstride) {
  __shared__ bf16 sAh[BM * BK], sAl[BM * BK], sBh[BN * BK], sBl[BN * BK];

  const int tid = threadIdx.x;
  const int lane = tid & 63, wid = tid >> 6;
  const int wr = wid >> 1, wc = wid & 1;          // wave -> 64x64 subtile
  const int z = blockIdx.z;
  const int brow = blockIdx.y * BM, bcol = blockIdx.x * BN;
  const int srow = tid >> 2;                      // staging row 0..63
  const int skk = (tid & 3) * 8;                  // staging k offset
  const int fr = lane & 15, fq = lane >> 4;       // fragment row / k-group

  const bf16* A_h = Ah_g + (long)z * a_bstride;
  const bf16* A_l = Al_g + (long)z * a_bstride;
  const bf16* B_h = Bh_g + (long)z * b_bstride;
  const bf16* B_l = Bl_g + (long)z * b_bstride;

  f32x4 acc[4][4] = {};

  for (int k0 = 0; k0 < D; k0 += BK) {
#pragma unroll
    for (int r = 0; r < 2; ++r) {
      const int row = r * 64 + srow;
      const long aoff = (long)(brow + row) * D + k0 + skk;
      const long boff = (long)(bcol + row) * D + k0 + skk;
      const int lbase = (r * 256 + wid * 64) * 8;   // wave-uniform LDS base
      __builtin_amdgcn_global_load_lds((const AS1 void*)(A_h + aoff), (AS3 void*)(sAh + lbase), 16, 0, 0);
      __builtin_amdgcn_global_load_lds((const AS1 void*)(A_l + aoff), (AS3 void*)(sAl + lbase), 16, 0, 0);
      __builtin_amdgcn_global_load_lds((const AS1 void*)(B_h + boff), (AS3 void*)(sBh + lbase), 16, 0, 0);
      __builtin_amdgcn_global_load_lds((const AS1 void*)(B_l + boff), (AS3 void*)(sBl + lbase), 16, 0, 0);
    }
    __syncthreads();

    bf16x8 ah[4], al[4];
#pragma unroll
    for (int m = 0; m < 4; ++m) {
      const int off = (wr * 64 + m * 16 + fr) * BK + fq * 8;
      ah[m] = *(const bf16x8*)&sAh[off];
      al[m] = *(const bf16x8*)&sAl[off];
    }
#pragma unroll
    for (int n = 0; n < 4; ++n) {
      const int off = (wc * 64 + n * 16 + fr) * BK + fq * 8;
      const bf16x8 bh = *(const bf16x8*)&sBh[off];
      const bf16x8 bl = *(const bf16x8*)&sBl[off];
#pragma unroll
      for (int m = 0; m < 4; ++m) {
        acc[m][n] = __builtin_amdgcn_mfma_f32_16x16x32_bf16(ah[m], bh, acc[m][n], 0, 0, 0);
        acc[m][n] = __builtin_amdgcn_mfma_f32_16x16x32_bf16(ah[m], bl, acc[m][n], 0, 0, 0);
        acc[m][n] = __builtin_amdgcn_mfma_f32_16x16x32_bf16(al[m], bh, acc[m][n], 0, 0, 0);
      }
    }
    __syncthreads();
  }

  // Epilogue. C/D frag layout: col = lane&15, row = (lane>>4)*4 + j  [m89-verified]
  if constexpr (EPI == 0) {
#pragma unroll
    for (int n = 0; n < 4; ++n) {
      const int col = bcol + wc * 64 + n * 16 + fr;
      const float bv = bias[col];
#pragma unroll
      for (int m = 0; m < 4; ++m) {
        const int row0 = brow + wr * 64 + m * 16 + fq * 4;
#pragma unroll
        for (int j = 0; j < 4; ++j) {
          const float c = acc[m][n][j] + bv;
          const bf16 h = (bf16)c;
          const bf16 l = (bf16)(c - (float)h);
          const long idx = (long)(row0 + j) * D + col;
          Ch[idx] = h;
          Cl[idx] = l;
        }
      }
    }
  } else {
    float* Cz = Cf + (long)z * c_bstride;
#pragma unroll
    for (int n = 0; n < 4; ++n) {
      const int col = bcol + wc * 64 + n * 16 + fr;
#pragma unroll
      for (int m = 0; m < 4; ++m) {
        const int row0 = brow + wr * 64 + m * 16 + fq * 4;
#pragma unroll
        for (int j = 0; j < 4; ++j) {
          const int row = row0 + j;
          Cz[(long)row * S + col] = acc[m][n][j] + bias[(long)row * S + col];
        }
      }
    }
  }
}

// ---------------------------------------------------------------------------
// Plain bf16 GEMM (PV): C[m,n] = sum_k A[m,k]*B[n,k], fp32 out
__global__ __launch_bounds__(256, 2) void gemm_plain(
    const bf16* __restrict__ A_g, long a_bstride,
    const bf16* __restrict__ B_g, long b_bstride,
    float* __restrict__ C, long c_bstride) {
  __shared__ bf16 sA[BM * BK], sB[BN * BK];

  const int tid = threadIdx.x;
  const int lane = tid & 63, wid = tid >> 6;
  const int wr = wid >> 1, wc = wid & 1;
  const int z = blockIdx.z;
  const int brow = blockIdx.y * BM, bcol = blockIdx.x * BN;
  const int srow = tid >> 2;
  const int skk = (tid & 3) * 8;
  const int fr = lane & 15, fq = lane >> 4;

  const bf16* A = A_g + (long)z * a_bstride;
  const bf16* B = B_g + (long)z * b_bstride;

  f32x4 acc[4][4] = {};

  for (int k0 = 0; k0 < S; k0 += BK) {
#pragma unroll
    for (int r = 0; r < 2; ++r) {
      const int row = r * 64 + srow;
      const long aoff = (long)(brow + row) * S + k0 + skk;
      const long boff = (long)(bcol + row) * S + k0 + skk;
      const int lbase = (r * 256 + wid * 64) * 8;
      __builtin_amdgcn_global_load_lds((const AS1 void*)(A + aoff), (AS3 void*)(sA + lbase), 16, 0, 0);
      __builtin_amdgcn_global_load_lds((const AS1 void*)(B + boff), (AS3 void*)(sB + lbase), 16, 0, 0);
    }
    __syncthreads();

    bf16x8 af[4];
#pragma unroll
    for (int m = 0; m < 4; ++m)
      af[m] = *(const bf16x8*)&sA[(wr * 64 + m * 16 + fr) * BK + fq * 8];
#pragma unroll
    for (int n = 0; n < 4; ++n) {
      const bf16x8 bf_ = *(const bf16x8*)&sB[(wc * 64 + n * 16 + fr) * BK + fq * 8];
#pragma unroll
      for (int m = 0; m < 4; ++m)
        acc[m][n] = __builtin_amdgcn_mfma_f32_16x16x32_bf16(af[m], bf_, acc[m][n], 0, 0, 0);
    }
    __syncthreads();
  }

  float* Cz = C + (long)z * c_bstride;
#pragma unroll
  for (int n = 0; n < 4; ++n) {
    const int col = bcol + wc * 64 + n * 16 + fr;
#pragma unroll
    for (int m = 0; m < 4; ++m) {
      const int row0 = brow + wr * 64 + m * 16 + fq * 4;
#pragma unroll
      for (int j = 0; j < 4; ++j)
        Cz[(long)(row0 + j) * D + col] = acc[m][n][j];
    }
  }
}

// ---------------------------------------------------------------------------
// Row softmax on attention (fp32, in place in d_out) + bf16 copy for PV.
// One 256-thread block per row of 1024.
__global__ __launch_bounds__(256) void softmax_rows(
    float* __restrict__ attn, bf16* __restrict__ attn_bf) {
  const long row = blockIdx.x;
  float* p = attn + row * 1024;
  const int tid = threadIdx.x, lane = tid & 63, wid = tid >> 6;

  f32x4 x = ((const f32x4*)p)[tid];
  float m = fmaxf(fmaxf(x[0], x[1]), fmaxf(x[2], x[3]));
#pragma unroll
  for (int off = 32; off; off >>= 1) m = fmaxf(m, __shfl_xor(m, off));
  __shared__ float redm[4];
  if (lane == 0) redm[wid] = m;
  __syncthreads();
  m = fmaxf(fmaxf(redm[0], redm[1]), fmaxf(redm[2], redm[3]));

  f32x4 e;
#pragma unroll
  for (int j = 0; j < 4; ++j) e[j] = __expf(x[j] - m);
  float s = e[0] + e[1] + e[2] + e[3];
#pragma unroll
  for (int off = 32; off; off >>= 1) s += __shfl_xor(s, off);
  __shared__ float reds[4];
  if (lane == 0) reds[wid] = s;
  __syncthreads();
  s = reds[0] + reds[1] + reds[2] + reds[3];

  const float inv = 1.0f / s;
  f32x4 r;
  bf16x4 rb;
#pragma unroll
  for (int j = 0; j < 4; ++j) {
    r[j] = e[j] * inv;
    rb[j] = (bf16)r[j];
  }
  ((f32x4*)p)[tid] = r;
  ((bf16x4*)(attn_bf + row * 1024))[tid] = rb;
}

// ---------------------------------------------------------------------------
extern "C" void kernel_launch(void* const* d_in, const int* in_sizes, int n_in,
                              void* d_out, int out_size, void* d_ws, size_t ws_size,
                              hipStream_t stream) {
  const float* query     = (const float*)d_in[0];
  const float* key       = (const float*)d_in[1];
  const float* value     = (const float*)d_in[2];
  const float* attn_bias = (const float*)d_in[3];
  const float* Wq        = (const float*)d_in[4];
  const float* bq        = (const float*)d_in[5];
  const float* Wk        = (const float*)d_in[6];
  const float* bk        = (const float*)d_in[7];

  float* out  = (float*)d_out;          // [16,1024,1024]
  float* attn = out + NBSD;             // [16,1024,1024]

  // ws carve (bf16 elements). Total = 6*NBSD + 4*D*D elems = 200 MiB.
  bf16* ws    = (bf16*)d_ws;
  bf16* q_hi  = ws;
  bf16* q_lo  = ws + NBSD;
  bf16* k_hi  = ws + 2 * NBSD;
  bf16* k_lo  = ws + 3 * NBSD;
  bf16* Wq_hi = ws + 4 * NBSD;
  bf16* Wq_lo = Wq_hi + (long)D * D;
  bf16* Wk_hi = Wq_lo + (long)D * D;
  bf16* Wk_lo = Wk_hi + (long)D * D;
  bf16* scr   = Wk_lo + (long)D * D;    // 2*NBSD scratch
  bf16* key_hi = scr;                   // key splits live here during proj...
  bf16* key_lo = scr + NBSD;
  bf16* valueT  = scr;                  // ...then reused for valueT / attn_bf
  bf16* attn_bf = scr + NBSD;
  // query splits live in d_out's `out` region (free until PV writes it)
  bf16* query_hi = (bf16*)d_out;
  bf16* query_lo = query_hi + NBSD;

  // 1) split conversions
  split_convert<<<2048, 256, 0, stream>>>(query, query_hi, query_lo, (int)(NBSD / 4));
  split_convert<<<2048, 256, 0, stream>>>(key, key_hi, key_lo, (int)(NBSD / 4));
  split_convert<<<512, 256, 0, stream>>>(Wq, Wq_hi, Wq_lo, D * D / 4);
  split_convert<<<512, 256, 0, stream>>>(Wk, Wk_hi, Wk_lo, D * D / 4);

  // 2) projections: [16384,1024] x [1024,1024]^T, split output
  dim3 gproj(D / BN, BATCH * S / BM, 1);
  gemm_split<0><<<gproj, 256, 0, stream>>>(query_hi, query_lo, 0, Wq_hi, Wq_lo, 0,
                                           bq, q_hi, q_lo, nullptr, 0);
  gemm_split<0><<<gproj, 256, 0, stream>>>(key_hi, key_lo, 0, Wk_hi, Wk_lo, 0,
                                           bk, k_hi, k_lo, nullptr, 0);

  // 3) value transpose (reuses key-split scratch; key splits now dead)
  transpose_convert<<<dim3(32, 32, 16), 256, 0, stream>>>(value, valueT);

  // 4) energy = q k^T + bias -> fp32 attention region of d_out
  dim3 gbat(S / BN, S / BM, BATCH);
  gemm_split<1><<<gbat, 256, 0, stream>>>(q_hi, q_lo, (long)S * D, k_hi, k_lo, (long)S * D,
                                          attn_bias, nullptr, nullptr, attn, (long)S * S);

  // 5) softmax in place + bf16 copy
  softmax_rows<<<BATCH * S, 256, 0, stream>>>(attn, attn_bf);

  // 6) out = attention @ value  (plain bf16)
  gemm_plain<<<gbat, 256, 0, stream>>>(attn_bf, (long)S * S, valueT, (long)D * S,
                                       out, (long)S * D);
}

// Round 2
// 544.686 us; speedup vs baseline: 1.0099x; 1.0099x over previous
//
#include <hip/hip_runtime.h>

// ---------------------------------------------------------------------------
// RVMixtureSynthesizers: q = query@Wq^T + bq ; k = key@Wk^T + bk
//   energy = q@k^T + attn_bias ; attention = softmax(energy) ; out = attention@value
// Outputs (concatenated in d_out): out [16,1024,1024] fp32, attention [16,1024,1024] fp32
//
// Precision: split-bf16 (hi+lo, 3 MFMA products) for proj and QK^T so energy is
// accurate to ~1e-3. PV uses plain bf16.
//
// R1 change: LDS chunk-XOR swizzle p = row*4 + (chunk ^ ((row>>1)&3)) applied
// BOTH sides (pre-swizzled global source for global_load_lds + swizzled frag
// read offset) -> ds_read_b128 goes 8-way-conflict -> conflict-free.
//
// Workspace need: 200 MiB exactly (6*BSD + 4*D*D bf16 elements).
// ---------------------------------------------------------------------------

#define AS1 __attribute__((address_space(1)))
#define AS3 __attribute__((address_space(3)))

typedef __bf16 bf16;
typedef __bf16 bf16x4 __attribute__((ext_vector_type(4)));
typedef __bf16 bf16x8 __attribute__((ext_vector_type(8)));
typedef float  f32x4  __attribute__((ext_vector_type(4)));

constexpr int BATCH = 16;
constexpr int S = 1024;
constexpr int D = 1024;
constexpr long NBSD = (long)BATCH * S * D;   // 16777216 elements

constexpr int BM = 128, BN = 128, BK = 32;

// ---------------------------------------------------------------------------
// fp32 -> (hi bf16, lo bf16) split conversion, vectorized x4
__global__ __launch_bounds__(256) void split_convert(
    const float* __restrict__ in, bf16* __restrict__ hi, bf16* __restrict__ lo, int n4) {
  int i = blockIdx.x * blockDim.x + threadIdx.x;
  int stride = gridDim.x * blockDim.x;
  for (; i < n4; i += stride) {
    f32x4 x = ((const f32x4*)in)[i];
    bf16x4 h, l;
#pragma unroll
    for (int j = 0; j < 4; ++j) {
      float v = x[j];
      bf16 hh = (bf16)v;
      h[j] = hh;
      l[j] = (bf16)(v - (float)hh);   // x - hi is exact in fp32
    }
    ((bf16x4*)hi)[i] = h;
    ((bf16x4*)lo)[i] = l;
  }
}

// ---------------------------------------------------------------------------
// value [b][t][d] fp32 -> valueT [b][d][t] bf16 (so PV GEMM gets B^T layout)
__global__ __launch_bounds__(256) void transpose_convert(
    const float* __restrict__ v, bf16* __restrict__ vT) {
  __shared__ float tile[32][33];
  const int b = blockIdx.z;
  const int t0 = blockIdx.y * 32, d0 = blockIdx.x * 32;
  const int tx = threadIdx.x & 31, ty = threadIdx.x >> 5;  // 32 x 8
  const float* src = v + (long)b * S * D;
#pragma unroll
  for (int i = 0; i < 4; ++i)
    tile[ty + i * 8][tx] = src[(long)(t0 + ty + i * 8) * D + d0 + tx];
  __syncthreads();
  bf16* dst = vT + (long)b * D * S;
#pragma unroll
  for (int i = 0; i < 4; ++i)
    dst[(long)(d0 + ty + i * 8) * S + t0 + tx] = (bf16)tile[tx][ty + i * 8];
}

// ---------------------------------------------------------------------------
// Split-bf16 GEMM: C[m,n] = sum_k (Ah+Al)[m,k] * (Bh+Bl)[n,k]  (B^T layout)
// EPI=0: proj — add bias[col], write split bf16 (Ch,Cl), ld=D
// EPI=1: energy — add bias[row*S+col] (attn_bias), write fp32 Cf (per-batch)
template <int EPI>
__global__ __launch_bounds__(256, 2) void gemm_split(
    const bf16* __restrict__ Ah_g, const bf16* __restrict__ Al_g, long a_bstride,
    const bf16* __restrict__ Bh_g, const bf16* __restrict__ Bl_g, long b_bstride,
    const float* __restrict__ bias,
    bf16* __restrict__ Ch, bf16* __restrict__ Cl,
    float* __restrict__ Cf, long c_bstride) {
  __shared__ bf16 sAh[BM * BK], sAl[BM * BK], sBh[BN * BK], sBl[BN * BK];

  const int tid = threadIdx.x;
  const int lane = tid & 63, wid = tid >> 6;
  const int wr = wid >> 1, wc = wid & 1;          // wave -> 64x64 subtile
  const int z = blockIdx.z;
  const int brow = blockIdx.y * BM, bcol = blockIdx.x * BN;
  const int srow = tid >> 2;                      // staging row 0..63
  const int csw8 = ((tid & 3) ^ ((srow >> 1) & 3)) * 8;  // swizzled k-chunk offset
  const int fr = lane & 15, fq = lane >> 4;       // fragment row / k-group
  const int fsw = (fr >> 1) & 3;                  // read-side swizzle (lane const)

  const bf16* A_h = Ah_g + (long)z * a_bstride;
  const bf16* A_l = Al_g + (long)z * a_bstride;
  const bf16* B_h = Bh_g + (long)z * b_bstride;
  const bf16* B_l = Bl_g + (long)z * b_bstride;

  f32x4 acc[4][4] = {};

  for (int k0 = 0; k0 < D; k0 += BK) {
#pragma unroll
    for (int r = 0; r < 2; ++r) {
      const int row = r * 64 + srow;
      const long aoff = (long)(brow + row) * D + k0 + csw8;
      const long boff = (long)(bcol + row) * D + k0 + csw8;
      const int lbase = (r * 256 + wid * 64) * 8;   // wave-uniform LDS base
      __builtin_amdgcn_global_load_lds((const AS1 void*)(A_h + aoff), (AS3 void*)(sAh + lbase), 16, 0, 0);
      __builtin_amdgcn_global_load_lds((const AS1 void*)(A_l + aoff), (AS3 void*)(sAl + lbase), 16, 0, 0);
      __builtin_amdgcn_global_load_lds((const AS1 void*)(B_h + boff), (AS3 void*)(sBh + lbase), 16, 0, 0);
      __builtin_amdgcn_global_load_lds((const AS1 void*)(B_l + boff), (AS3 void*)(sBl + lbase), 16, 0, 0);
    }
    __syncthreads();

    bf16x8 ah[4], al[4];
#pragma unroll
    for (int m = 0; m < 4; ++m) {
      const int off = ((wr * 64 + m * 16 + fr) * 4 + (fq ^ fsw)) * 8;
      ah[m] = *(const bf16x8*)&sAh[off];
      al[m] = *(const bf16x8*)&sAl[off];
    }
#pragma unroll
    for (int n = 0; n < 4; ++n) {
      const int off = ((wc * 64 + n * 16 + fr) * 4 + (fq ^ fsw)) * 8;
      const bf16x8 bh = *(const bf16x8*)&sBh[off];
      const bf16x8 bl = *(const bf16x8*)&sBl[off];
#pragma unroll
      for (int m = 0; m < 4; ++m) {
        acc[m][n] = __builtin_amdgcn_mfma_f32_16x16x32_bf16(ah[m], bh, acc[m][n], 0, 0, 0);
        acc[m][n] = __builtin_amdgcn_mfma_f32_16x16x32_bf16(ah[m], bl, acc[m][n], 0, 0, 0);
        acc[m][n] = __builtin_amdgcn_mfma_f32_16x16x32_bf16(al[m], bh, acc[m][n], 0, 0, 0);
      }
    }
    __syncthreads();
  }

  // Epilogue. C/D frag layout: col = lane&15, row = (lane>>4)*4 + j  [m89-verified]
  if constexpr (EPI == 0) {
#pragma unroll
    for (int n = 0; n < 4; ++n) {
      const int col = bcol + wc * 64 + n * 16 + fr;
      const float bv = bias[col];
#pragma unroll
      for (int m = 0; m < 4; ++m) {
        const int row0 = brow + wr * 64 + m * 16 + fq * 4;
#pragma unroll
        for (int j = 0; j < 4; ++j) {
          const float c = acc[m][n][j] + bv;
          const bf16 h = (bf16)c;
          const bf16 l = (bf16)(c - (float)h);
          const long idx = (long)(row0 + j) * D + col;
          Ch[idx] = h;
          Cl[idx] = l;
        }
      }
    }
  } else {
    float* Cz = Cf + (long)z * c_bstride;
#pragma unroll
    for (int n = 0; n < 4; ++n) {
      const int col = bcol + wc * 64 + n * 16 + fr;
#pragma unroll
      for (int m = 0; m < 4; ++m) {
        const int row0 = brow + wr * 64 + m * 16 + fq * 4;
#pragma unroll
        for (int j = 0; j < 4; ++j) {
          const int row = row0 + j;
          Cz[(long)row * S + col] = acc[m][n][j] + bias[(long)row * S + col];
        }
      }
    }
  }
}

// ---------------------------------------------------------------------------
// Plain bf16 GEMM (PV): C[m,n] = sum_k A[m,k]*B[n,k], fp32 out
__global__ __launch_bounds__(256, 2) void gemm_plain(
    const bf16* __restrict__ A_g, long a_bstride,
    const bf16* __restrict__ B_g, long b_bstride,
    float* __restrict__ C, long c_bstride) {
  __shared__ bf16 sA[BM * BK], sB[BN * BK];

  const int tid = threadIdx.x;
  const int lane = tid & 63, wid = tid >> 6;
  const int wr = wid >> 1, wc = wid & 1;
  const int z = blockIdx.z;
  const int brow = blockIdx.y * BM, bcol = blockIdx.x * BN;
  const int srow = tid >> 2;
  const int csw8 = ((tid & 3) ^ ((srow >> 1) & 3)) * 8;
  const int fr = lane & 15, fq = lane >> 4;
  const int fsw = (fr >> 1) & 3;

  const bf16* A = A_g + (long)z * a_bstride;
  const bf16* B = B_g + (long)z * b_bstride;

  f32x4 acc[4][4] = {};

  for (int k0 = 0; k0 < S; k0 += BK) {
#pragma unroll
    for (int r = 0; r < 2; ++r) {
      const int row = r * 64 + srow;
      const long aoff = (long)(brow + row) * S + k0 + csw8;
      const long boff = (long)(bcol + row) * S + k0 + csw8;
      const int lbase = (r * 256 + wid * 64) * 8;
      __builtin_amdgcn_global_load_lds((const AS1 void*)(A + aoff), (AS3 void*)(sA + lbase), 16, 0, 0);
      __builtin_amdgcn_global_load_lds((const AS1 void*)(B + boff), (AS3 void*)(sB + lbase), 16, 0, 0);
    }
    __syncthreads();

    bf16x8 af[4];
#pragma unroll
    for (int m = 0; m < 4; ++m)
      af[m] = *(const bf16x8*)&sA[((wr * 64 + m * 16 + fr) * 4 + (fq ^ fsw)) * 8];
#pragma unroll
    for (int n = 0; n < 4; ++n) {
      const bf16x8 bf_ = *(const bf16x8*)&sB[((wc * 64 + n * 16 + fr) * 4 + (fq ^ fsw)) * 8];
#pragma unroll
      for (int m = 0; m < 4; ++m)
        acc[m][n] = __builtin_amdgcn_mfma_f32_16x16x32_bf16(af[m], bf_, acc[m][n], 0, 0, 0);
    }
    __syncthreads();
  }

  float* Cz = C + (long)z * c_bstride;
#pragma unroll
  for (int n = 0; n < 4; ++n) {
    const int col = bcol + wc * 64 + n * 16 + fr;
#pragma unroll
    for (int m = 0; m < 4; ++m) {
      const int row0 = brow + wr * 64 + m * 16 + fq * 4;
#pragma unroll
      for (int j = 0; j < 4; ++j)
        Cz[(long)(row0 + j) * D + col] = acc[m][n][j];
    }
  }
}

// ---------------------------------------------------------------------------
// Row softmax on attention (fp32, in place in d_out) + bf16 copy for PV.
// One 256-thread block per row of 1024.
__global__ __launch_bounds__(256) void softmax_rows(
    float* __restrict__ attn, bf16* __restrict__ attn_bf) {
  const long row = blockIdx.x;
  float* p = attn + row * 1024;
  const int tid = threadIdx.x, lane = tid & 63, wid = tid >> 6;

  f32x4 x = ((const f32x4*)p)[tid];
  float m = fmaxf(fmaxf(x[0], x[1]), fmaxf(x[2], x[3]));
#pragma unroll
  for (int off = 32; off; off >>= 1) m = fmaxf(m, __shfl_xor(m, off));
  __shared__ float redm[4];
  if (lane == 0) redm[wid] = m;
  __syncthreads();
  m = fmaxf(fmaxf(redm[0], redm[1]), fmaxf(redm[2], redm[3]));

  f32x4 e;
#pragma unroll
  for (int j = 0; j < 4; ++j) e[j] = __expf(x[j] - m);
  float s = e[0] + e[1] + e[2] + e[3];
#pragma unroll
  for (int off = 32; off; off >>= 1) s += __shfl_xor(s, off);
  __shared__ float reds[4];
  if (lane == 0) reds[wid] = s;
  __syncthreads();
  s = reds[0] + reds[1] + reds[2] + reds[3];

  const float inv = 1.0f / s;
  f32x4 r;
  bf16x4 rb;
#pragma unroll
  for (int j = 0; j < 4; ++j) {
    r[j] = e[j] * inv;
    rb[j] = (bf16)r[j];
  }
  ((f32x4*)p)[tid] = r;
  ((bf16x4*)(attn_bf + row * 1024))[tid] = rb;
}

// ---------------------------------------------------------------------------
extern "C" void kernel_launch(void* const* d_in, const int* in_sizes, int n_in,
                              void* d_out, int out_size, void* d_ws, size_t ws_size,
                              hipStream_t stream) {
  const float* query     = (const float*)d_in[0];
  const float* key       = (const float*)d_in[1];
  const float* value     = (const float*)d_in[2];
  const float* attn_bias = (const float*)d_in[3];
  const float* Wq        = (const float*)d_in[4];
  const float* bq        = (const float*)d_in[5];
  const float* Wk        = (const float*)d_in[6];
  const float* bk        = (const float*)d_in[7];

  float* out  = (float*)d_out;          // [16,1024,1024]
  float* attn = out + NBSD;             // [16,1024,1024]

  // ws carve (bf16 elements). Total = 6*NBSD + 4*D*D elems = 200 MiB.
  bf16* ws    = (bf16*)d_ws;
  bf16* q_hi  = ws;
  bf16* q_lo  = ws + NBSD;
  bf16* k_hi  = ws + 2 * NBSD;
  bf16* k_lo  = ws + 3 * NBSD;
  bf16* Wq_hi = ws + 4 * NBSD;
  bf16* Wq_lo = Wq_hi + (long)D * D;
  bf16* Wk_hi = Wq_lo + (long)D * D;
  bf16* Wk_lo = Wk_hi + (long)D * D;
  bf16* scr   = Wk_lo + (long)D * D;    // 2*NBSD scratch
  bf16* key_hi = scr;                   // key splits live here during proj...
  bf16* key_lo = scr + NBSD;
  bf16* valueT  = scr;                  // ...then reused for valueT / attn_bf
  bf16* attn_bf = scr + NBSD;
  // query splits live in d_out's `out` region (free until PV writes it)
  bf16* query_hi = (bf16*)d_out;
  bf16* query_lo = query_hi + NBSD;

  // 1) split conversions
  split_convert<<<2048, 256, 0, stream>>>(query, query_hi, query_lo, (int)(NBSD / 4));
  split_convert<<<2048, 256, 0, stream>>>(key, key_hi, key_lo, (int)(NBSD / 4));
  split_convert<<<512, 256, 0, stream>>>(Wq, Wq_hi, Wq_lo, D * D / 4);
  split_convert<<<512, 256, 0, stream>>>(Wk, Wk_hi, Wk_lo, D * D / 4);

  // 2) projections: [16384,1024] x [1024,1024]^T, split output
  dim3 gproj(D / BN, BATCH * S / BM, 1);
  gemm_split<0><<<gproj, 256, 0, stream>>>(query_hi, query_lo, 0, Wq_hi, Wq_lo, 0,
                                           bq, q_hi, q_lo, nullptr, 0);
  gemm_split<0><<<gproj, 256, 0, stream>>>(key_hi, key_lo, 0, Wk_hi, Wk_lo, 0,
                                           bk, k_hi, k_lo, nullptr, 0);

  // 3) value transpose (reuses key-split scratch; key splits now dead)
  transpose_convert<<<dim3(32, 32, 16), 256, 0, stream>>>(value, valueT);

  // 4) energy = q k^T + bias -> fp32 attention region of d_out
  dim3 gbat(S / BN, S / BM, BATCH);
  gemm_split<1><<<gbat, 256, 0, stream>>>(q_hi, q_lo, (long)S * D, k_hi, k_lo, (long)S * D,
                                          attn_bias, nullptr, nullptr, attn, (long)S * S);

  // 5) softmax in place + bf16 copy
  softmax_rows<<<BATCH * S, 256, 0, stream>>>(attn, attn_bf);

  // 6) out = attention @ value  (plain bf16)
  gemm_plain<<<gbat, 256, 0, stream>>>(attn_bf, (long)S * S, valueT, (long)D * S,
                                       out, (long)S * D);
}

// Round 3
// 468.282 us; speedup vs baseline: 1.1747x; 1.1632x over previous
//
#include <hip/hip_runtime.h>

// ---------------------------------------------------------------------------
// RVMixtureSynthesizers: q = query@Wq^T + bq ; k = key@Wk^T + bk
//   energy = q@k^T + attn_bias ; attention = softmax(energy) ; out = attention@value
// Outputs: out [16,1024,1024] fp32, attention [16,1024,1024] fp32 (concat in d_out)
//
// R2: all GEMMs ported to 256x256-tile phased schedule (T3+T4 counted vmcnt,
// T5 setprio, T1 XCD swizzle) on top of R1's verified conflict-free LDS swizzle.
// Split-bf16 (hh+hl+lh) for proj and QK^T; PV plain bf16.
// ---------------------------------------------------------------------------

#define AS1 __attribute__((address_space(1)))
#define AS3 __attribute__((address_space(3)))
#define VMCNT(n) asm volatile("s_waitcnt vmcnt(" #n ")" ::: "memory")

typedef __bf16 bf16;
typedef __bf16 bf16x4 __attribute__((ext_vector_type(4)));
typedef __bf16 bf16x8 __attribute__((ext_vector_type(8)));
typedef float  f32x4  __attribute__((ext_vector_type(4)));

constexpr int BATCH = 16;
constexpr int S = 1024;
constexpr int D = 1024;
constexpr long NBSD = (long)BATCH * S * D;   // 16777216

constexpr int GBM = 256, GBN = 256, GBK = 32;
constexpr int NTK = 1024 / GBK;              // 32 K-tiles
constexpr int ARR = GBM * GBK;               // 8192 elems = 16 KB per array

__device__ __forceinline__ void stage16(const bf16* src, const bf16* dst) {
  __builtin_amdgcn_global_load_lds((const AS1 void*)src, (AS3 void*)dst, 16, 0, 0);
}

// ---------------------------------------------------------------------------
// fp32 -> (hi bf16, lo bf16) split conversion, vectorized x4
__global__ __launch_bounds__(256) void split_convert(
    const float* __restrict__ in, bf16* __restrict__ hi, bf16* __restrict__ lo, int n4) {
  int i = blockIdx.x * blockDim.x + threadIdx.x;
  int stride = gridDim.x * blockDim.x;
  for (; i < n4; i += stride) {
    f32x4 x = ((const f32x4*)in)[i];
    bf16x4 h, l;
#pragma unroll
    for (int j = 0; j < 4; ++j) {
      float v = x[j];
      bf16 hh = (bf16)v;
      h[j] = hh;
      l[j] = (bf16)(v - (float)hh);
    }
    ((bf16x4*)hi)[i] = h;
    ((bf16x4*)lo)[i] = l;
  }
}

// ---------------------------------------------------------------------------
// value [b][t][d] fp32 -> valueT [b][d][t] bf16
__global__ __launch_bounds__(256) void transpose_convert(
    const float* __restrict__ v, bf16* __restrict__ vT) {
  __shared__ float tile[32][33];
  const int b = blockIdx.z;
  const int t0 = blockIdx.y * 32, d0 = blockIdx.x * 32;
  const int tx = threadIdx.x & 31, ty = threadIdx.x >> 5;
  const float* src = v + (long)b * S * D;
#pragma unroll
  for (int i = 0; i < 4; ++i)
    tile[ty + i * 8][tx] = src[(long)(t0 + ty + i * 8) * D + d0 + tx];
  __syncthreads();
  bf16* dst = vT + (long)b * D * S;
#pragma unroll
  for (int i = 0; i < 4; ++i)
    dst[(long)(d0 + ty + i * 8) * S + t0 + tx] = (bf16)tile[tx][ty + i * 8];
}

// ---------------------------------------------------------------------------
// Phased split-bf16 GEMM. BM=BN=256, BK=32, 512 thr (8 waves 2x4, 128x64/wave).
// LDS: 2 slots x {Ah,Al,Bh,Bl} x 16KB = 128KB.
// Per K-tile, 3 phases: P1 hh (read Ah,Bh; stage next Ah,Bh; vmcnt 6)
//                       P2 hl (read Bl;    stage next Bl;    vmcnt 6)
//                       P3 lh (read Al;    stage next Al;    vmcnt 4)
// EPI=0: proj (col bias, split-bf16 out).  EPI=1: energy (full bias, fp32 out).
template <int EPI>
__global__ __launch_bounds__(512, 2) void gemm8_split(
    const bf16* __restrict__ Ah_g, const bf16* __restrict__ Al_g, long a_bs,
    const bf16* __restrict__ Bh_g, const bf16* __restrict__ Bl_g, long b_bs,
    const float* __restrict__ bias,
    bf16* __restrict__ Ch, bf16* __restrict__ Cl,
    float* __restrict__ Cf, long c_bs) {
  __shared__ bf16 lds[2 * 4 * ARR];   // 128 KB

  const int tid = threadIdx.x;
  const int lane = tid & 63, wid = tid >> 6;
  const int wr = wid >> 2, wc = wid & 3;          // 2x4 wave grid
  const int fr = lane & 15, fq = lane >> 4;
  const int fsw = (fr >> 1) & 3;

  // T1 bijective XCD swizzle (nwg=256)
  const int w = blockIdx.x;
  const int swz = (w & 7) * 32 + (w >> 3);
  int z, by, bx;
  if constexpr (EPI == 0) { z = 0; by = swz >> 2; bx = swz & 3; }
  else { z = swz >> 4; by = (swz >> 2) & 3; bx = swz & 3; }
  const long brow = (long)by * GBM, bcol = (long)bx * GBN;

  const bf16* A_h = Ah_g + (long)z * a_bs;
  const bf16* A_l = Al_g + (long)z * a_bs;
  const bf16* B_h = Bh_g + (long)z * b_bs;
  const bf16* B_l = Bl_g + (long)z * b_bs;

  const int srow = tid >> 2;                                  // 0..127
  const int csw = ((tid & 3) ^ ((srow >> 1) & 3)) * 8;        // source pre-swizzle
  const long asrc = (brow + srow) * 1024 + csw;
  const long bsrc = (bcol + srow) * 1024 + csw;
  const int dstoff = wid * 512;                               // wave-uniform, +lane*8 by HW

  // fragment LDS element offsets (chunk-XOR swizzled, conflict-free per R1/R2 PMC)
  const int aoffb = (wr * 128 + fr) * 32 + (fq ^ fsw) * 8;    // + m*512
  const int boffb = (wc * 64 + fr) * 32 + (fq ^ fsw) * 8;     // + n*512

  f32x4 acc[8][4] = {};

#define STG(slot, arr, base, koff, rr) \
  stage16((base) + (koff) + (long)(rr) * 131072, \
          lds + ((slot) * 4 + (arr)) * ARR + (rr) * 4096 + dstoff)

  // prologue: tile 0 into slot 0, issue order = phase order
  STG(0, 0, A_h + asrc, 0, 0); STG(0, 0, A_h + asrc, 0, 1);
  STG(0, 2, B_h + bsrc, 0, 0); STG(0, 2, B_h + bsrc, 0, 1);
  STG(0, 3, B_l + bsrc, 0, 0); STG(0, 3, B_l + bsrc, 0, 1);
  STG(0, 1, A_l + asrc, 0, 0); STG(0, 1, A_l + asrc, 0, 1);
  VMCNT(4);                      // Ah,Bh(0) done; Bl,Al(0) in flight
  __builtin_amdgcn_s_barrier();

  for (int t = 0; t < NTK; ++t) {
    const int cur = t & 1, nxt = cur ^ 1;
    const long kn = (long)(t + 1) * GBK;
    const bf16* lA_h = lds + (cur * 4 + 0) * ARR;
    const bf16* lA_l = lds + (cur * 4 + 1) * ARR;
    const bf16* lB_h = lds + (cur * 4 + 2) * ARR;
    const bf16* lB_l = lds + (cur * 4 + 3) * ARR;

    bf16x8 ah[8], bh[4];
    // ---------------- P1: hh ----------------
#pragma unroll
    for (int m = 0; m < 8; ++m) ah[m] = *(const bf16x8*)&lA_h[aoffb + m * 512];
#pragma unroll
    for (int n = 0; n < 4; ++n) bh[n] = *(const bf16x8*)&lB_h[boffb + n * 512];
    if (t + 1 < NTK) {
      STG(nxt, 0, A_h + asrc, kn, 0); STG(nxt, 0, A_h + asrc, kn, 1);
      STG(nxt, 2, B_h + bsrc, kn, 0); STG(nxt, 2, B_h + bsrc, kn, 1);
      VMCNT(6);                  // Bl(t) done (Al(t)+AhBh(t+1)=6 in flight)
    } else { VMCNT(2); }         // tail: Bl(t) done (Al(t)=2 in flight)
    __builtin_amdgcn_sched_barrier(0);
    __builtin_amdgcn_s_barrier();
    __builtin_amdgcn_s_setprio(1);
#pragma unroll
    for (int n = 0; n < 4; ++n)
#pragma unroll
      for (int m = 0; m < 8; ++m)
        acc[m][n] = __builtin_amdgcn_mfma_f32_16x16x32_bf16(ah[m], bh[n], acc[m][n], 0, 0, 0);
    __builtin_amdgcn_s_setprio(0);
    __builtin_amdgcn_sched_barrier(0);
    __builtin_amdgcn_s_barrier();

    // ---------------- P2: hl ----------------
    bf16x8 bl[4];
#pragma unroll
    for (int n = 0; n < 4; ++n) bl[n] = *(const bf16x8*)&lB_l[boffb + n * 512];
    if (t + 1 < NTK) {
      STG(nxt, 3, B_l + bsrc, kn, 0); STG(nxt, 3, B_l + bsrc, kn, 1);
      VMCNT(6);                  // Al(t) done (AhBh(t+1)+Bl(t+1)=6 in flight)
    } else { VMCNT(0); }         // tail: Al(t) done
    __builtin_amdgcn_sched_barrier(0);
    __builtin_amdgcn_s_barrier();
    __builtin_amdgcn_s_setprio(1);
#pragma unroll
    for (int n = 0; n < 4; ++n)
#pragma unroll
      for (int m = 0; m < 8; ++m)
        acc[m][n] = __builtin_amdgcn_mfma_f32_16x16x32_bf16(ah[m], bl[n], acc[m][n], 0, 0, 0);
    __builtin_amdgcn_s_setprio(0);
    __builtin_amdgcn_sched_barrier(0);
    __builtin_amdgcn_s_barrier();

    // ---------------- P3: lh ----------------
    bf16x8 al[8];
#pragma unroll
    for (int m = 0; m < 8; ++m) al[m] = *(const bf16x8*)&lA_l[aoffb + m * 512];
    if (t + 1 < NTK) {
      STG(nxt, 1, A_l + asrc, kn, 0); STG(nxt, 1, A_l + asrc, kn, 1);
      VMCNT(4);                  // AhBh(t+1) done (Bl+Al(t+1)=4 in flight)
    }
    __builtin_amdgcn_sched_barrier(0);
    __builtin_amdgcn_s_barrier();
    __builtin_amdgcn_s_setprio(1);
#pragma unroll
    for (int n = 0; n < 4; ++n)
#pragma unroll
      for (int m = 0; m < 8; ++m)
        acc[m][n] = __builtin_amdgcn_mfma_f32_16x16x32_bf16(al[m], bh[n], acc[m][n], 0, 0, 0);
    __builtin_amdgcn_s_setprio(0);
    __builtin_amdgcn_sched_barrier(0);
    __builtin_amdgcn_s_barrier();
  }
#undef STG

  // Epilogue. C/D frag: col = lane&15, row = (lane>>4)*4 + j
  if constexpr (EPI == 0) {
#pragma unroll
    for (int n = 0; n < 4; ++n) {
      const long col = bcol + wc * 64 + n * 16 + fr;
      const float bv = bias[col];
#pragma unroll
      for (int m = 0; m < 8; ++m) {
        const long row0 = brow + wr * 128 + m * 16 + fq * 4;
#pragma unroll
        for (int j = 0; j < 4; ++j) {
          const float c = acc[m][n][j] + bv;
          const bf16 h = (bf16)c;
          const bf16 l = (bf16)(c - (float)h);
          const long idx = (row0 + j) * 1024 + col;
          Ch[idx] = h;
          Cl[idx] = l;
        }
      }
    }
  } else {
    float* Cz = Cf + (long)z * c_bs;
#pragma unroll
    for (int n = 0; n < 4; ++n) {
      const long col = bcol + wc * 64 + n * 16 + fr;
#pragma unroll
      for (int m = 0; m < 8; ++m) {
        const long row0 = brow + wr * 128 + m * 16 + fq * 4;
#pragma unroll
        for (int j = 0; j < 4; ++j) {
          const long row = row0 + j;
          Cz[row * 1024 + col] = acc[m][n][j] + bias[row * 1024 + col];
        }
      }
    }
  }
}

// ---------------------------------------------------------------------------
// Phased plain bf16 GEMM (PV). 3 slots x {A,B} x 16KB = 96KB, lookahead 2,
// one phase per K-tile (32 MFMA), steady wait vmcnt(4).
__global__ __launch_bounds__(512, 2) void gemm8_plain(
    const bf16* __restrict__ A_g, long a_bs,
    const bf16* __restrict__ B_g, long b_bs,
    float* __restrict__ C, long c_bs) {
  __shared__ bf16 lds[3 * 2 * ARR];   // 96 KB

  const int tid = threadIdx.x;
  const int lane = tid & 63, wid = tid >> 6;
  const int wr = wid >> 2, wc = wid & 3;
  const int fr = lane & 15, fq = lane >> 4;
  const int fsw = (fr >> 1) & 3;

  const int w = blockIdx.x;
  const int swz = (w & 7) * 32 + (w >> 3);
  const int z = swz >> 4, by = (swz >> 2) & 3, bx = swz & 3;
  const long brow = (long)by * GBM, bcol = (long)bx * GBN;

  const bf16* A = A_g + (long)z * a_bs;
  const bf16* B = B_g + (long)z * b_bs;

  const int srow = tid >> 2;
  const int csw = ((tid & 3) ^ ((srow >> 1) & 3)) * 8;
  const long asrc = (brow + srow) * 1024 + csw;
  const long bsrc = (bcol + srow) * 1024 + csw;
  const int dstoff = wid * 512;

  const int aoffb = (wr * 128 + fr) * 32 + (fq ^ fsw) * 8;
  const int boffb = (wc * 64 + fr) * 32 + (fq ^ fsw) * 8;

  f32x4 acc[8][4] = {};

#define STG2(slot, arr, base, koff, rr) \
  stage16((base) + (koff) + (long)(rr) * 131072, \
          lds + ((slot) * 2 + (arr)) * ARR + (rr) * 4096 + dstoff)

  // prologue: tiles 0 and 1
  STG2(0, 0, A + asrc, 0, 0);  STG2(0, 0, A + asrc, 0, 1);
  STG2(0, 1, B + bsrc, 0, 0);  STG2(0, 1, B + bsrc, 0, 1);
  STG2(1, 0, A + asrc, 32, 0); STG2(1, 0, A + asrc, 32, 1);
  STG2(1, 1, B + bsrc, 32, 0); STG2(1, 1, B + bsrc, 32, 1);
  VMCNT(4);                     // tile0 done; tile1 in flight
  __builtin_amdgcn_s_barrier();

  int cur = 0, st = 2;
  for (int t = 0; t < NTK; ++t) {
    const bf16* lA = lds + (cur * 2 + 0) * ARR;
    const bf16* lB = lds + (cur * 2 + 1) * ARR;
    bf16x8 ah[8], bh[4];
#pragma unroll
    for (int m = 0; m < 8; ++m) ah[m] = *(const bf16x8*)&lA[aoffb + m * 512];
#pragma unroll
    for (int n = 0; n < 4; ++n) bh[n] = *(const bf16x8*)&lB[boffb + n * 512];
    if (t + 2 < NTK) {
      const long kn = (long)(t + 2) * GBK;
      STG2(st, 0, A + asrc, kn, 0); STG2(st, 0, A + asrc, kn, 1);
      STG2(st, 1, B + bsrc, kn, 0); STG2(st, 1, B + bsrc, kn, 1);
      VMCNT(4);                 // tile t+1 done (t+2's 4 in flight)
    } else { VMCNT(0); }        // tail drain
    __builtin_amdgcn_sched_barrier(0);
    __builtin_amdgcn_s_barrier();
    __builtin_amdgcn_s_setprio(1);
#pragma unroll
    for (int n = 0; n < 4; ++n)
#pragma unroll
      for (int m = 0; m < 8; ++m)
        acc[m][n] = __builtin_amdgcn_mfma_f32_16x16x32_bf16(ah[m], bh[n], acc[m][n], 0, 0, 0);
    __builtin_amdgcn_s_setprio(0);
    __builtin_amdgcn_sched_barrier(0);
    __builtin_amdgcn_s_barrier();
    cur = (cur == 2) ? 0 : cur + 1;
    st  = (st == 2)  ? 0 : st + 1;
  }
#undef STG2

  float* Cz = C + (long)z * c_bs;
#pragma unroll
  for (int n = 0; n < 4; ++n) {
    const long col = bcol + wc * 64 + n * 16 + fr;
#pragma unroll
    for (int m = 0; m < 8; ++m) {
      const long row0 = brow + wr * 128 + m * 16 + fq * 4;
#pragma unroll
      for (int j = 0; j < 4; ++j)
        Cz[(row0 + j) * 1024 + col] = acc[m][n][j];
    }
  }
}

// ---------------------------------------------------------------------------
// Row softmax (fp32 in place) + bf16 copy for PV.
__global__ __launch_bounds__(256) void softmax_rows(
    float* __restrict__ attn, bf16* __restrict__ attn_bf) {
  const long row = blockIdx.x;
  float* p = attn + row * 1024;
  const int tid = threadIdx.x, lane = tid & 63, wid = tid >> 6;

  f32x4 x = ((const f32x4*)p)[tid];
  float m = fmaxf(fmaxf(x[0], x[1]), fmaxf(x[2], x[3]));
#pragma unroll
  for (int off = 32; off; off >>= 1) m = fmaxf(m, __shfl_xor(m, off));
  __shared__ float redm[4];
  if (lane == 0) redm[wid] = m;
  __syncthreads();
  m = fmaxf(fmaxf(redm[0], redm[1]), fmaxf(redm[2], redm[3]));

  f32x4 e;
#pragma unroll
  for (int j = 0; j < 4; ++j) e[j] = __expf(x[j] - m);
  float s = e[0] + e[1] + e[2] + e[3];
#pragma unroll
  for (int off = 32; off; off >>= 1) s += __shfl_xor(s, off);
  __shared__ float reds[4];
  if (lane == 0) reds[wid] = s;
  __syncthreads();
  s = reds[0] + reds[1] + reds[2] + reds[3];

  const float inv = 1.0f / s;
  f32x4 r;
  bf16x4 rb;
#pragma unroll
  for (int j = 0; j < 4; ++j) {
    r[j] = e[j] * inv;
    rb[j] = (bf16)r[j];
  }
  ((f32x4*)p)[tid] = r;
  ((bf16x4*)(attn_bf + row * 1024))[tid] = rb;
}

// ---------------------------------------------------------------------------
extern "C" void kernel_launch(void* const* d_in, const int* in_sizes, int n_in,
                              void* d_out, int out_size, void* d_ws, size_t ws_size,
                              hipStream_t stream) {
  const float* query     = (const float*)d_in[0];
  const float* key       = (const float*)d_in[1];
  const float* value     = (const float*)d_in[2];
  const float* attn_bias = (const float*)d_in[3];
  const float* Wq        = (const float*)d_in[4];
  const float* bq        = (const float*)d_in[5];
  const float* Wk        = (const float*)d_in[6];
  const float* bk        = (const float*)d_in[7];

  float* out  = (float*)d_out;          // [16,1024,1024]
  float* attn = out + NBSD;             // [16,1024,1024]

  // ws carve (bf16 elements). Total = 6*NBSD + 4*D*D = 200 MiB.
  bf16* ws    = (bf16*)d_ws;
  bf16* q_hi  = ws;
  bf16* q_lo  = ws + NBSD;
  bf16* k_hi  = ws + 2 * NBSD;
  bf16* k_lo  = ws + 3 * NBSD;
  bf16* Wq_hi = ws + 4 * NBSD;
  bf16* Wq_lo = Wq_hi + (long)D * D;
  bf16* Wk_hi = Wq_lo + (long)D * D;
  bf16* Wk_lo = Wk_hi + (long)D * D;
  bf16* scr   = Wk_lo + (long)D * D;    // 2*NBSD scratch
  bf16* key_hi = scr;
  bf16* key_lo = scr + NBSD;
  bf16* valueT  = scr;                  // reused after key splits die
  bf16* attn_bf = scr + NBSD;
  bf16* query_hi = (bf16*)d_out;        // lives in `out` region until PV
  bf16* query_lo = query_hi + NBSD;

  // 1) split conversions
  split_convert<<<2048, 256, 0, stream>>>(query, query_hi, query_lo, (int)(NBSD / 4));
  split_convert<<<2048, 256, 0, stream>>>(key, key_hi, key_lo, (int)(NBSD / 4));
  split_convert<<<512, 256, 0, stream>>>(Wq, Wq_hi, Wq_lo, D * D / 4);
  split_convert<<<512, 256, 0, stream>>>(Wk, Wk_hi, Wk_lo, D * D / 4);

  // 2) projections: [16384,1024] x [1024,1024]^T (grid 64x4 = 256 blocks)
  gemm8_split<0><<<256, 512, 0, stream>>>(query_hi, query_lo, 0, Wq_hi, Wq_lo, 0,
                                          bq, q_hi, q_lo, nullptr, 0);
  gemm8_split<0><<<256, 512, 0, stream>>>(key_hi, key_lo, 0, Wk_hi, Wk_lo, 0,
                                          bk, k_hi, k_lo, nullptr, 0);

  // 3) value transpose (key splits now dead)
  transpose_convert<<<dim3(32, 32, 16), 256, 0, stream>>>(value, valueT);

  // 4) energy = q k^T + bias (grid 16 z x 4x4 = 256 blocks)
  gemm8_split<1><<<256, 512, 0, stream>>>(q_hi, q_lo, (long)S * D, k_hi, k_lo, (long)S * D,
                                          attn_bias, nullptr, nullptr, attn, (long)S * S);

  // 5) softmax in place + bf16 copy
  softmax_rows<<<BATCH * S, 256, 0, stream>>>(attn, attn_bf);

  // 6) out = attention @ value
  gemm8_plain<<<256, 512, 0, stream>>>(attn_bf, (long)S * S, valueT, (long)D * S,
                                       out, (long)S * D);
}